// Round 10
// baseline (129.255 us; speedup 1.0000x reference)
//
#include <hip/hip_runtime.h>
#include <math.h>

#define NN 4096
#define DD 256
#define EE 131072
#define MAXD 128
#define SP 132          // sS row stride; 132%32==4 -> conflict-free

typedef __attribute__((ext_vector_type(8))) short short8;
typedef __attribute__((ext_vector_type(4))) float float4v;

__device__ __forceinline__ unsigned short f2bf(float f){
    unsigned u = __float_as_uint(f);
    return (unsigned short)((u + 0x7fffu + ((u >> 16) & 1u)) >> 16);   // RNE
}
__device__ __forceinline__ float blo(unsigned u){ return __uint_as_float(u << 16); }
__device__ __forceinline__ float bhi(unsigned u){ return __uint_as_float(u & 0xffff0000u); }

// ---------------- K1: pack weights to MFMA fragments + zero adj ----------------
__device__ __forceinline__ void pack_one(const float* __restrict__ src, unsigned short* __restrict__ dst, int e){
    int lane = e & 63;
    int row = ((e >> 9) << 4) + (lane & 15);
    int k0 = ((e >> 6) & 7) * 32 + ((lane >> 4) << 3);
    const float* p = src + row * DD + k0;
    short8 v;
    #pragma unroll
    for (int j = 0; j < 8; ++j) v[j] = (short)f2bf(p[j]);
    ((short8*)dst)[e] = v;
}

__global__ void k_packw(const float* __restrict__ ipw, const float* __restrict__ ow, const float* __restrict__ lw,
                        unsigned short* __restrict__ bipw, unsigned short* __restrict__ bow,
                        unsigned short* __restrict__ blw, unsigned* __restrict__ adj){
    int e = blockIdx.x * 256 + threadIdx.x;       // 40960 threads
    for (int i = e; i < 524288; i += 40960) adj[i] = 0u;   // zero 2MB adj
    if (e < 24576)       pack_one(ipw, bipw, e);
    else if (e < 32768)  pack_one(ow,  bow,  e - 24576);
    else                 pack_one(lw,  blw,  e - 32768);
}

// ---------------- K2: QKV GEMM (Q fp32, K/V bf16) + fused edge scatter ----------------
__global__ void __launch_bounds__(256) k_gqkv(const float* __restrict__ emb, const unsigned short* __restrict__ Bp,
                                              const float* __restrict__ bias, float* __restrict__ qf,
                                              unsigned short* __restrict__ kb, unsigned short* __restrict__ vb,
                                              const int* __restrict__ ei, unsigned* __restrict__ adj){
    __shared__ float sA[16 * 260];
    int bx = blockIdx.x, by = blockIdx.y;
    int t = threadIdx.x, w = t >> 6, lane = t & 63;

    // fire-and-forget edge scatter (adj zeroed by k_packw)
    int gid = (by * gridDim.x + bx) * 256 + t;
    if (gid < EE){
        int s = ei[gid], d = ei[EE + gid];
        if (s != d){
            atomicOr(&adj[s * 128 + (d >> 5)], 1u << (d & 31));
            atomicOr(&adj[d * 128 + (s >> 5)], 1u << (s & 31));
        }
    }

    #pragma unroll
    for (int i = 0; i < 16; ++i)
        sA[i * 260 + t] = emb[(bx * 16 + i) * 256 + t];
    __syncthreads();

    int arow = lane & 15, ak0 = (lane >> 4) << 3;
    short8 af[8];
    #pragma unroll
    for (int s = 0; s < 8; ++s){
        const float* p = &sA[arow * 260 + s * 32 + ak0];
        #pragma unroll
        for (int j = 0; j < 8; ++j) af[s][j] = (short)f2bf(p[j]);
    }

    const short8* B8 = (const short8*)Bp;
    float4v acc[4];
    #pragma unroll
    for (int c = 0; c < 4; ++c) acc[c] = (float4v){0.f, 0.f, 0.f, 0.f};
    #pragma unroll
    for (int s = 0; s < 8; ++s){
        #pragma unroll
        for (int c = 0; c < 4; ++c){
            int to = by * 16 + w * 4 + c;
            acc[c] = __builtin_amdgcn_mfma_f32_16x16x32_bf16(af[s], B8[(to * 8 + s) * 64 + lane], acc[c], 0, 0, 0);
        }
    }
    int q = lane >> 4, col = lane & 15;
    #pragma unroll
    for (int c = 0; c < 4; ++c){
        int o = (w * 4 + c) * 16 + col;
        float bo = bias[by * 256 + o];
        #pragma unroll
        for (int r = 0; r < 4; ++r){
            int node = bx * 16 + q * 4 + r;
            float val = acc[c][r] + bo;
            if (by == 0)      qf[node * 256 + o] = val;
            else if (by == 1) kb[node * 256 + o] = f2bf(val);
            else              vb[node * 256 + o] = f2bf(val);
        }
    }
}

// 32-dim bf16 dot against fp32 q fragments
__device__ __forceinline__ float dot32(const float4* qa, uint4 a, uint4 b, uint4 c, uint4 d){
    float s;
    s  = qa[0].x*blo(a.x) + qa[0].y*bhi(a.x) + qa[0].z*blo(a.y) + qa[0].w*bhi(a.y);
    s += qa[1].x*blo(a.z) + qa[1].y*bhi(a.z) + qa[1].z*blo(a.w) + qa[1].w*bhi(a.w);
    s += qa[2].x*blo(b.x) + qa[2].y*bhi(b.x) + qa[2].z*blo(b.y) + qa[2].w*bhi(b.y);
    s += qa[3].x*blo(b.z) + qa[3].y*bhi(b.z) + qa[3].z*blo(b.w) + qa[3].w*bhi(b.w);
    s += qa[4].x*blo(c.x) + qa[4].y*bhi(c.x) + qa[4].z*blo(c.y) + qa[4].w*bhi(c.y);
    s += qa[5].x*blo(c.z) + qa[5].y*bhi(c.z) + qa[5].z*blo(c.w) + qa[5].w*bhi(c.w);
    s += qa[6].x*blo(d.x) + qa[6].y*bhi(d.x) + qa[6].z*blo(d.y) + qa[6].w*bhi(d.y);
    s += qa[7].x*blo(d.z) + qa[7].y*bhi(d.z) + qa[7].z*blo(d.w) + qa[7].w*bhi(d.w);
    return s;
}

// ---------------- K3: fused attention + tail. 1024 threads = 16 waves; 8 nodes, 2 waves/node ----
// wave pair (2w, 2w+1): even wave = heads 0-3 (dims 0-127), odd = heads 4-7 (dims 128-255).
// Attention is barrier-free per wave; 8192 waves total -> 32 waves/CU.
__global__ void __launch_bounds__(1024, 8) k_attn_tail(
        const float* __restrict__ qf, const unsigned short* __restrict__ kb,
        const unsigned short* __restrict__ vb, const unsigned* __restrict__ adj,
        const float* __restrict__ emb,
        const unsigned short* __restrict__ Bow, const float* __restrict__ ob,
        const unsigned short* __restrict__ Blw, const float* __restrict__ lb,
        const float* __restrict__ g, const float* __restrict__ beta,
        float* __restrict__ out){
    __shared__ float  sS[8][8][SP];      // 33.8 KB scores; later reused as xs[16*264]
    __shared__ int    sNbr[16][MAXD];    // 8 KB (each wave its own copy of its node's list)
    __shared__ short8 sPk[512];          // 8 KB fragment staging (16 rows; rows 8-15 dead)
    __shared__ float  sInv[8][8];
    __shared__ int    sDeg[8];
    int bx = blockIdx.x, t = threadIdx.x;
    int wv = t >> 6, lane = t & 63;
    int w = wv >> 1;                     // node slot 0..7
    int p = wv & 1;                      // head-half parity
    int n0 = bx * 8, n = n0 + w;
    float* xs = (float*)sS;

    // ======== ATTENTION ========
    // --- neighbor extraction (done by BOTH waves of the pair, into private sNbr[wv]) ---
    uint2 aw = ((const uint2*)(adj + n * 128))[lane];
    int cnt = __popc(aw.x) + __popc(aw.y);
    int pre = cnt;
    #pragma unroll
    for (int off = 1; off < 64; off <<= 1){
        int tmp = __shfl_up(pre, off);
        if (lane >= off) pre += tmp;
    }
    int tot = __shfl(pre, 63);
    int dg = (tot < MAXD) ? tot : MAXD;
    if (p == 0 && lane == 63) sDeg[w] = dg;
    int base = pre - cnt;
    int mb = lane * 64;
    unsigned b0 = aw.x, b1 = aw.y;
    while (b0){ int b = __ffs(b0) - 1; b0 &= b0 - 1u; if (base < MAXD) sNbr[wv][base] = mb + b; base++; }
    mb += 32;
    while (b1){ int b = __ffs(b1) - 1; b1 &= b1 - 1u; if (base < MAXD) sNbr[wv][base] = mb + b; base++; }

    if (dg > 0){
        asm volatile("s_waitcnt lgkmcnt(0)" ::: "memory");

        // --- scores: lane = (js = lane>>2 in [0,16), hl = lane&3); abs head ah = p*4+hl ---
        int js = lane >> 2, hl = lane & 3, ah = p * 4 + hl;
        float4 qa[8];
        const float4* q4 = (const float4*)(qf + n * 256 + ah * 32);
        #pragma unroll
        for (int i = 0; i < 8; ++i) qa[i] = q4[i];
        for (int jb = 0; jb < dg; jb += 16){
            int j = jb + js;
            bool v = j < dg;
            int m = v ? sNbr[wv][j] : sNbr[wv][0];
            const uint4* kr = (const uint4*)(kb + m * 256) + ah * 4;
            uint4 a0 = kr[0], a1 = kr[1], a2 = kr[2], a3 = kr[3];
            float s = dot32(qa, a0, a1, a2, a3) * 0.17677669529663687f;   // 1/sqrt(32)
            if (v) sS[w][ah][j] = s;
        }
        asm volatile("s_waitcnt lgkmcnt(0)" ::: "memory");

        // --- softmax over this wave's 4 heads: lane = (hl, i2 = lane>>2); 16 lanes/head ---
        int i2 = lane >> 2;
        float m1 = -1e30f;
        for (int j = i2; j < dg; j += 16) m1 = fmaxf(m1, sS[w][ah][j]);
        m1 = fmaxf(m1, __shfl_xor(m1, 4));
        m1 = fmaxf(m1, __shfl_xor(m1, 8));
        m1 = fmaxf(m1, __shfl_xor(m1, 16));
        m1 = fmaxf(m1, __shfl_xor(m1, 32));
        float sum = 0.f;
        for (int j = i2; j < dg; j += 16){ float e = __expf(sS[w][ah][j] - m1); sS[w][ah][j] = e; sum += e; }
        sum += __shfl_xor(sum, 4);
        sum += __shfl_xor(sum, 8);
        sum += __shfl_xor(sum, 16);
        sum += __shfl_xor(sum, 32);
        if (i2 == 0) sInv[w][ah] = 1.0f / sum;
        asm volatile("s_waitcnt lgkmcnt(0)" ::: "memory");

        // --- values: lane = (jp = lane>>5, dq = lane&31); dims d0..d0+3 of this half ---
        int jp = lane >> 5, dq = lane & 31;
        int d0 = p * 128 + dq * 4;
        int ahv = d0 >> 5;               // abs head of these dims
        int vidx = d0 >> 2;              // uint2 index within V row
        const uint2* vb2 = (const uint2*)vb;
        float4 O = {0.f, 0.f, 0.f, 0.f};
        int j = jp;
        for (; j + 6 < dg; j += 8){      // 4-way unroll over stride-2 j
            int m0 = sNbr[wv][j], m1_ = sNbr[wv][j + 2], m2 = sNbr[wv][j + 4], m3 = sNbr[wv][j + 6];
            uint2 u0 = vb2[m0 * 64 + vidx];
            uint2 u1 = vb2[m1_ * 64 + vidx];
            uint2 u2 = vb2[m2 * 64 + vidx];
            uint2 u3 = vb2[m3 * 64 + vidx];
            float w0 = sS[w][ahv][j], w1 = sS[w][ahv][j + 2], w2 = sS[w][ahv][j + 4], w3 = sS[w][ahv][j + 6];
            O.x += w0 * blo(u0.x) + w1 * blo(u1.x) + w2 * blo(u2.x) + w3 * blo(u3.x);
            O.y += w0 * bhi(u0.x) + w1 * bhi(u1.x) + w2 * bhi(u2.x) + w3 * bhi(u3.x);
            O.z += w0 * blo(u0.y) + w1 * blo(u1.y) + w2 * blo(u2.y) + w3 * blo(u3.y);
            O.w += w0 * bhi(u0.y) + w1 * bhi(u1.y) + w2 * bhi(u2.y) + w3 * bhi(u3.y);
        }
        for (; j < dg; j += 2){
            uint2 u = vb2[sNbr[wv][j] * 64 + vidx];
            float wgt = sS[w][ahv][j];
            O.x += wgt * blo(u.x); O.y += wgt * bhi(u.x);
            O.z += wgt * blo(u.y); O.w += wgt * bhi(u.y);
        }
        // combine the two j-parities in-register
        O.x += __shfl_xor(O.x, 32); O.y += __shfl_xor(O.y, 32);
        O.z += __shfl_xor(O.z, 32); O.w += __shfl_xor(O.w, 32);
        if (lane < 32){
            float inv = sInv[w][ahv];
            int s  = d0 >> 5;
            int l2 = ((d0 >> 3) & 3) * 16 + w;
            uint2 pk;
            pk.x = (unsigned)f2bf(O.x * inv) | ((unsigned)f2bf(O.y * inv) << 16);
            pk.y = (unsigned)f2bf(O.z * inv) | ((unsigned)f2bf(O.w * inv) << 16);
            ((uint2*)sPk)[(s * 64 + l2) * 2 + ((d0 & 7) >> 2)] = pk;
        }
    }
    __syncthreads();

    // ======== TAIL: out-proj + passthrough -> pack -> lin -> LayerNorm -> GELU ========
    // 16 waves x 1 col-tile each = 256 cols; C rows 0-7 valid (A rows 8-15 garbage, contained)
    const short8* B8 = (const short8*)Bow;
    float4v acc = (float4v){0.f, 0.f, 0.f, 0.f};
    #pragma unroll
    for (int s = 0; s < 8; ++s){
        short8 a = sPk[s * 64 + lane];
        acc = __builtin_amdgcn_mfma_f32_16x16x32_bf16(a, B8[(wv * 8 + s) * 64 + lane], acc, 0, 0, 0);
    }
    int q = lane >> 4, col = lane & 15;
    {
        int o = wv * 16 + col;
        float bo = ob[o];
        #pragma unroll
        for (int r = 0; r < 4; ++r){
            int row = q * 4 + r;                 // 0..15; only 0..7 valid
            if (row < 8){
                float x = acc[r] + bo;
                if (sDeg[row] == 0) x = emb[(n0 + row) * 256 + o];
                xs[row * 264 + o] = x;
            }
        }
    }
    __syncthreads();

    // pack x -> bf16 fragments (512 entries; rows 8-15 zeroed); threads 512+ idle
    if (t < 512){
        int l2 = t & 63, s = t >> 6;
        int mm = l2 & 15, k0 = s * 32 + ((l2 >> 4) << 3);
        short8 v;
        if (mm < 8){
            #pragma unroll
            for (int j = 0; j < 8; ++j) v[j] = (short)f2bf(xs[mm * 264 + k0 + j]);
        } else {
            #pragma unroll
            for (int j = 0; j < 8; ++j) v[j] = 0;
        }
        sPk[t] = v;
    }
    __syncthreads();

    // lin MFMA
    const short8* B2 = (const short8*)Blw;
    float4v acc2 = (float4v){0.f, 0.f, 0.f, 0.f};
    #pragma unroll
    for (int s = 0; s < 8; ++s){
        short8 a = sPk[s * 64 + lane];
        acc2 = __builtin_amdgcn_mfma_f32_16x16x32_bf16(a, B2[(wv * 8 + s) * 64 + lane], acc2, 0, 0, 0);
    }
    __syncthreads();                     // pack's xs reads done; reuse xs as ys
    {
        int o = wv * 16 + col;
        float bo = lb[o];
        #pragma unroll
        for (int r = 0; r < 4; ++r){
            int row = q * 4 + r;
            if (row < 8) xs[row * 264 + o] = acc2[r] + bo;
        }
    }
    __syncthreads();

    // LayerNorm + exact GELU: waves 0-7, one row each; 64 lanes x 4 cols
    if (wv < 8){
        int i = lane;
        float s1 = 0.f, s2 = 0.f;
        #pragma unroll
        for (int jj = 0; jj < 4; ++jj){ float v = xs[wv * 264 + i + 64 * jj]; s1 += v; s2 += v * v; }
        #pragma unroll
        for (int off = 32; off > 0; off >>= 1){ s1 += __shfl_xor(s1, off); s2 += __shfl_xor(s2, off); }
        float mu = s1 * (1.0f / 256.0f);
        float var = s2 * (1.0f / 256.0f) - mu * mu;
        float rs = rsqrtf(fmaxf(var, 0.f) + 1e-5f);
        int nbase = (n0 + wv) * 256;
        #pragma unroll
        for (int jj = 0; jj < 4; ++jj){
            int cc = i + 64 * jj;
            float z = (xs[wv * 264 + cc] - mu) * rs * g[cc] + beta[cc];
            out[nbase + cc] = 0.5f * z * (1.0f + erff(z * 0.70710678118654752f));
        }
    }
}

extern "C" void kernel_launch(void* const* d_in, const int* in_sizes, int n_in,
                              void* d_out, int out_size, void* d_ws, size_t ws_size,
                              hipStream_t stream){
    const float* emb = (const float*)d_in[0];
    const int*   ei  = (const int*)d_in[1];
    const float* ipw = (const float*)d_in[2];
    const float* ipb = (const float*)d_in[3];
    const float* ow  = (const float*)d_in[4];
    const float* ob  = (const float*)d_in[5];
    const float* lw  = (const float*)d_in[6];
    const float* lb  = (const float*)d_in[7];
    const float* g   = (const float*)d_in[8];
    const float* bet = (const float*)d_in[9];

    char* ws = (char*)d_ws;
    unsigned*       adj  = (unsigned*)(ws);                    // 2 MiB
    unsigned short* bipw = (unsigned short*)(ws + 2113536);    // 384 KiB
    unsigned short* bow  = (unsigned short*)(ws + 2506752);    // 128 KiB
    unsigned short* blw  = (unsigned short*)(ws + 2637824);    // 128 KiB
    float*          qf   = (float*)(ws + 2768896);             // 4 MiB
    unsigned short* kb   = (unsigned short*)(ws + 6963200);    // 2 MiB
    unsigned short* vb   = (unsigned short*)(ws + 9060352);    // 2 MiB

    k_packw    <<<160, 256, 0, stream>>>(ipw, ow, lw, bipw, bow, blw, adj);
    k_gqkv     <<<dim3(256, 3), 256, 0, stream>>>(emb, bipw, ipb, qf, kb, vb, ei, adj);
    k_attn_tail<<<512, 1024, 0, stream>>>(qf, kb, vb, adj, emb, bow, ob, blw, lb, g, bet, (float*)d_out);
}